// Round 7
// baseline (634.471 us; speedup 1.0000x reference)
//
#include <hip/hip_runtime.h>
#include <math.h>

typedef __attribute__((ext_vector_type(8))) short bf16x8;
typedef __attribute__((ext_vector_type(4))) float f32x4;
typedef __attribute__((ext_vector_type(4))) unsigned u32x4;

// ---------------- workspace layout (u32 offsets) ----------------
#define H1P_OFF  0ull
#define H2P_OFF  35143680ull
#define WP2_OFF  53526528ull
#define WP3_OFF  54050816ull
#define EQ_OFF   54247424ull   // packed emb, lane-contiguous, 32768 u32
#define EN_OFF   54280192ull
#define HIST_OFF 54280704ull
#define SSE_OFF  54281216ull

__device__ inline unsigned short f2bf(float f) {
  unsigned u = __builtin_bit_cast(unsigned, f);
  return (unsigned short)((u + 0x7fffu + ((u >> 16) & 1u)) >> 16);  // RNE
}
__device__ inline float bf2f(unsigned short h) {
  return __builtin_bit_cast(float, (unsigned)h << 16);
}
__device__ inline unsigned packsplit(float v) {
  unsigned short h = f2bf(v);
  unsigned short l = f2bf(v - bf2f(h));
  return (unsigned)h | ((unsigned)l << 16);
}
__device__ inline int swz(int row, int g) {  // byte offset in a [rows][32 u32] tile
  return ((row << 7) + (g << 4)) ^ ((row & 7) << 4);
}
#define SEL_HI 0x05040100u
#define SEL_LO 0x07060302u
__device__ inline bf16x8 mkfrag(const u32x4 p, const u32x4 q, unsigned sel) {
  u32x4 r;
  r[0] = __builtin_amdgcn_perm(p[1], p[0], sel);
  r[1] = __builtin_amdgcn_perm(p[3], p[2], sel);
  r[2] = __builtin_amdgcn_perm(q[1], q[0], sel);
  r[3] = __builtin_amdgcn_perm(q[3], q[2], sel);
  return __builtin_bit_cast(bf16x8, r);
}

// ======= weight repack: lane-contiguous per (ks, frag, j) 1KB blocks =========
__global__ void pack_wq2_k(const float* __restrict__ w, unsigned* __restrict__ wq) {
  int i = blockIdx.x * 256 + threadIdx.x;
  if (i >= 524288) return;
  int e = i & 3, l = (i >> 2) & 63, j = (i >> 8) & 1, fg = (i >> 9) & 15, ks = i >> 13;
  int row = fg * 16 + (l & 15);
  int k = ks * 32 + (l >> 4) * 8 + j * 4 + e;
  wq[i] = packsplit(w[row * 2048 + k]);
}
__global__ void pack_wq3_k(const float* __restrict__ w, unsigned* __restrict__ wq) {
  int i = blockIdx.x * 256 + threadIdx.x;
  if (i >= 196608) return;
  int e = i & 3, l = (i >> 2) & 63, j = (i >> 8) & 1, fg = (i >> 9) & 3, ks = i >> 11;
  int row = fg * 16 + (l & 15);
  int k = ks * 32 + (l >> 4) * 8 + j * 4 + e;
  int ci = k / 12, rb = k - ci * 12, kh = rb >> 2, kw = rb & 3;
  wq[i] = (kw < 3) ? packsplit(w[((row * 256 + ci) * 3 + kh) * 3 + kw]) : 0u;
}
// emb repack for VQ MFMA: fg 0..31 (512 rows / 16), ks 0..1 (K=64)
__global__ void pack_eq_k(const float* __restrict__ emb, unsigned* __restrict__ eq,
                          float* __restrict__ enorm) {
  int i = blockIdx.x * 256 + threadIdx.x;
  if (i < 32768) {
    int e = i & 3, l = (i >> 2) & 63, j = (i >> 8) & 1, fg = (i >> 9) & 31, ks = i >> 14;
    int row = fg * 16 + (l & 15);
    int d = ks * 32 + (l >> 4) * 8 + j * 4 + e;
    eq[i] = packsplit(emb[row * 64 + d]);
  }
  if (i < 512) {
    float s = 0.f;
#pragma unroll
    for (int d = 0; d < 64; ++d) { float e = emb[i * 64 + d]; s += e * e; }
    enorm[i] = s;
  }
}

// ================= halo zeroing for padded activation planes =================
__global__ void halo_k(unsigned* __restrict__ h1p, unsigned* __restrict__ h2p) {
  int i = blockIdx.x * 256 + threadIdx.x;
  if (i < 2048 * 520) {
    int p = i / 520, c = i - p * 520; int r, cc;
    if (c < 132)      { r = 0;   cc = c; }
    else if (c < 264) { r = 129; cc = c - 132; }
    else if (c < 392) { r = c - 264 + 1; cc = 0; }
    else              { r = c - 392 + 1; cc = 129; }
    h1p[(size_t)p * 130 * 132 + r * 132 + cc] = 0u;
  } else {
    int j = i - 2048 * 520;
    if (j >= 4096 * 328) return;
    int p = j / 328, c = j - p * 328; int r, cc;
    if (c < 68)       { r = 0;  cc = c; }
    else if (c < 136) { r = 65; cc = c - 68; }
    else { int c2 = c - 136; int which = c2 >> 6; r = 1 + (c2 & 63);
           cc = (which == 0) ? 0 : (which == 1 ? 65 : 66); }
    h2p[(size_t)p * 66 * 68 + r * 68 + cc] = 0u;
  }
}

// ================= conv1: 3->128, 4x4 s2 p1, fp32 vector ====
__global__ __launch_bounds__(256) void conv1_k(const float* __restrict__ x,
                                               const float* __restrict__ w,
                                               const float* __restrict__ bias,
                                               unsigned* __restrict__ out) {
  const int tx = threadIdx.x, ty = threadIdx.y;
  const int tile_x = blockIdx.x, tile_y = blockIdx.y, b = blockIdx.z;
  __shared__ float xs[3][34][35];
  const int tid = ty * 16 + tx;
  const int iy0 = tile_y * 32 - 1, ix0 = tile_x * 32 - 1;
  for (int idx = tid; idx < 3 * 1156; idx += 256) {
    int ci = idx / 1156; int rem = idx - ci * 1156;
    int r = rem / 34;    int c = rem - r * 34;
    int iy = iy0 + r, ix = ix0 + c;
    float v = 0.f;
    if (iy >= 0 && iy < 256 && ix >= 0 && ix < 256)
      v = x[((b * 3 + ci) * 256 + iy) * 256 + ix];
    xs[ci][r][c] = v;
  }
  __syncthreads();
  float p[48];
#pragma unroll
  for (int ci = 0; ci < 3; ++ci)
#pragma unroll
    for (int kh = 0; kh < 4; ++kh)
#pragma unroll
      for (int kw = 0; kw < 4; ++kw)
        p[ci * 16 + kh * 4 + kw] = xs[ci][2 * ty + kh][2 * tx + kw];
  const int Y = tile_y * 16 + ty, X = tile_x * 16 + tx;
  for (int co = 0; co < 128; ++co) {
    float acc = bias[co];
#pragma unroll
    for (int t = 0; t < 48; ++t) acc += p[t] * w[co * 48 + t];
    float v = acc > 0.f ? acc : 0.f;
    out[((size_t)(b * 128 + co) * 130 + (Y + 1)) * 132 + (X + 1)] = packsplit(v);
  }
}

// ====== pipelined implicit-GEMM conv, split-bf16 MFMA (unchanged from R5) =====
template <int IC, int KHW, int OC, int IHP, int IWP, int S, int NWX, int NWC,
          int OSR, int OSP, int OPAD, bool SPLIT_OUT>
__global__ __launch_bounds__(256, 2) void convmm_k(const unsigned* __restrict__ inp,
                                                   const unsigned* __restrict__ wq,
                                                   const float* __restrict__ bias,
                                                   unsigned* __restrict__ outp,
                                                   float* __restrict__ outf) {
  constexpr int K = IC * KHW;
  constexpr int KSTEPS = K / 32;
  constexpr int FGTOT = OC / 16;
  constexpr int NFRAG = OC / NWC / 16;
  constexpr int MR = 64 * NWX;
  constexpr int CELLS = MR / 32;
  constexpr int ABYTES = MR * 128;
  constexpr int LOG2NWX = (NWX == 2) ? 1 : 0;
  constexpr int YBITS = 6 - LOG2NWX;

  __shared__ char smem[2 * ABYTES];

  const int tid = threadIdx.x, l = tid & 63, wv = tid >> 6;
  const int bb = blockIdx.x >> YBITS;
  const int y0 = blockIdx.x & ((1 << YBITS) - 1);
  const int rsel = l & 15, g0 = (l >> 4) * 2;
  const int mbase = (wv & (NWX - 1)) * 64;
  const int fgbase = (wv >> LOG2NWX) * NFRAG;
  const int nbase = fgbase * 16;

  const int arow = tid & (MR - 1);
  int qs[CELLS];
  const unsigned* abase[CELLS];
#pragma unroll
  for (int c = 0; c < CELLS; ++c) {
    if constexpr (NWX == 1) qs[c] = (tid >> 6) + c * 4;
    else                    qs[c] = (tid >> 7) * 4 + c;
    if constexpr (KHW == 16) {
      int ci0 = qs[c] >> 2, kh = qs[c] & 3;
      abase[c] = inp + (((size_t)bb * IC + ci0) * IHP + (S * y0 + kh)) * IWP + S * arow;
    }
  }

  f32x4 acc[NFRAG][4];
#pragma unroll
  for (int nf = 0; nf < NFRAG; ++nf)
#pragma unroll
    for (int xf = 0; xf < 4; ++xf) acc[nf][xf] = (f32x4){0.f, 0.f, 0.f, 0.f};

  unsigned av[CELLS][4];
  u32x4 brA[NFRAG][2], brB[NFRAG][2];

  auto loadA = [&](int ks) {
#pragma unroll
    for (int c = 0; c < CELLS; ++c) {
      if constexpr (KHW == 16) {
        const unsigned* p = abase[c];
        av[c][0] = p[0]; av[c][1] = p[1]; av[c][2] = p[2]; av[c][3] = p[3];
        abase[c] += (size_t)2 * IHP * IWP;
      } else {
        int k = ks * 32 + qs[c] * 4;
        int ci = (k * 5462) >> 16;
        int rb = k - ci * 12;
        int kh = rb >> 2;
        int yl = arow >> 6, x = arow & 63;
        const unsigned* p = inp + (((size_t)bb * IC + ci) * IHP + (y0 * 2 + yl + kh)) * IWP + x;
        av[c][0] = p[0]; av[c][1] = p[1]; av[c][2] = p[2]; av[c][3] = p[3];
      }
    }
  };
  auto writeA = [&](int buf) {
    char* base = smem + buf * ABYTES;
#pragma unroll
    for (int c = 0; c < CELLS; ++c) {
      int wb = (arow << 7) + ((qs[c] ^ (arow & 7)) << 4);
      *(u32x4*)(base + wb) = *(u32x4*)&av[c][0];
    }
  };
  auto loadB = [&](int ks, u32x4 (&br)[NFRAG][2]) {
#pragma unroll
    for (int nf = 0; nf < NFRAG; ++nf)
#pragma unroll
      for (int j = 0; j < 2; ++j)
        br[nf][j] = *(const u32x4*)(wq + (((size_t)((ks * FGTOT + fgbase + nf) * 2 + j)) << 8)
                                       + (l << 2));
  };
  auto step = [&](int ks, u32x4 (&cur)[NFRAG][2], u32x4 (&nxt)[NFRAG][2]) {
    const bool has = (ks + 1 < KSTEPS);
    if (has) { loadB(ks + 1, nxt); loadA(ks + 1); }
    const char* bA = smem + (ks & 1) * ABYTES;
    u32x4 ar[4][2];
#pragma unroll
    for (int xf = 0; xf < 4; ++xf) {
      int row = mbase + xf * 16 + rsel;
      ar[xf][0] = *(const u32x4*)(bA + swz(row, g0));
      ar[xf][1] = *(const u32x4*)(bA + swz(row, g0 + 1));
    }
    bf16x8 ah[4], al[4];
#pragma unroll
    for (int xf = 0; xf < 4; ++xf) {
      ah[xf] = mkfrag(ar[xf][0], ar[xf][1], SEL_HI);
      al[xf] = mkfrag(ar[xf][0], ar[xf][1], SEL_LO);
    }
#pragma unroll
    for (int nf = 0; nf < NFRAG; ++nf) {
      bf16x8 wh = mkfrag(cur[nf][0], cur[nf][1], SEL_HI);
      bf16x8 wl = mkfrag(cur[nf][0], cur[nf][1], SEL_LO);
#pragma unroll
      for (int xf = 0; xf < 4; ++xf) {
        acc[nf][xf] = __builtin_amdgcn_mfma_f32_16x16x32_bf16(wh, ah[xf], acc[nf][xf], 0, 0, 0);
        acc[nf][xf] = __builtin_amdgcn_mfma_f32_16x16x32_bf16(wh, al[xf], acc[nf][xf], 0, 0, 0);
        acc[nf][xf] = __builtin_amdgcn_mfma_f32_16x16x32_bf16(wl, ah[xf], acc[nf][xf], 0, 0, 0);
      }
    }
    if (has) writeA((ks & 1) ^ 1);
    __syncthreads();
  };

  loadB(0, brA);
  loadA(0);
  writeA(0);
  __syncthreads();

#pragma unroll 1
  for (int ks = 0; ks < KSTEPS; ks += 2) {
    step(ks, brA, brB);
    step(ks + 1, brB, brA);
  }

#pragma unroll
  for (int nf = 0; nf < NFRAG; ++nf) {
    int n0 = nbase + nf * 16 + (l >> 4) * 4;
#pragma unroll
    for (int xf = 0; xf < 4; ++xf) {
      int m = mbase + xf * 16 + rsel;
      int yl = m >> 6, xo = m & 63;
      int yout = y0 * NWX + yl;
#pragma unroll
      for (int r = 0; r < 4; ++r) {
        float v = acc[nf][xf][r] + bias[n0 + r];
        if constexpr (SPLIT_OUT) {
          if (v < 0.f) v = 0.f;
          outp[((size_t)bb * OC + n0 + r) * OSP + (size_t)(yout + OPAD) * OSR + (xo + OPAD)] =
              packsplit(v);
        } else {
          outf[((size_t)bb * OC + n0 + r) * OSP + (size_t)yout * OSR + xo] = v;
        }
      }
    }
  }
}

// ============ VQ via MFMA: dists GEMM + argmin + quantize + hist + sse ========
// flat_z is a RAW reshape of z [B,C,H,W] -> [-1, 64]: each VQ vector is a
// contiguous x-line z[b,c,h,:]. Block = 64 consecutive flat rows = 16KB
// contiguous z. scores = emb @ z_rows^T via split-bf16 MFMA; dist = enorm-2*score.
__global__ __launch_bounds__(256, 2) void vqmm_k(float* __restrict__ zq,
                                                 const float* __restrict__ emb,
                                                 const unsigned* __restrict__ eq,
                                                 const float* __restrict__ enorm,
                                                 unsigned* __restrict__ hist,
                                                 float* __restrict__ gsse) {
  const int tid = threadIdx.x, l = tid & 63, wv = tid >> 6;
  float* zsrc = zq + (size_t)blockIdx.x * 4096;   // rows [blk*64, blk*64+64)

  __shared__ float zf[64][64];       // fp32 copy [n][d]
  __shared__ unsigned zp[4096];      // packed swizzled [n][d-groups]
  __shared__ float candd[4][64];
  __shared__ int   candi[4][64];
  __shared__ int   idxf[64];

  // ---- stage 1: fully-contiguous fp32 load (16KB) ----
#pragma unroll
  for (int p = 0; p < 4; ++p) {
    int idx = p * 256 + tid;               // float4 index
    float4 v = *(const float4*)(zsrc + (size_t)idx * 4);
    int n = idx >> 4, d0 = (idx & 15) * 4;
    zf[n][d0 + 0] = v.x; zf[n][d0 + 1] = v.y;
    zf[n][d0 + 2] = v.z; zf[n][d0 + 3] = v.w;
  }
  __syncthreads();
  // ---- stage 2: pack + swizzle (row n, d-group g stored at g^(n&15)) ----
#pragma unroll
  for (int p = 0; p < 16; ++p) {
    int idx = p * 256 + tid;
    int n = idx >> 6, d = idx & 63;
    zp[(n << 6) + ((((d >> 2) ^ (n & 15)) << 2) | (d & 3))] = packsplit(zf[n][d]);
  }
  __syncthreads();

  // ---- MFMA: wave wv covers embeddings [wv*128, wv*128+128) ----
  f32x4 acc[8][4];
#pragma unroll
  for (int nf = 0; nf < 8; ++nf)
#pragma unroll
    for (int xf = 0; xf < 4; ++xf) acc[nf][xf] = (f32x4){0.f, 0.f, 0.f, 0.f};

  const int rsel = l & 15;
#pragma unroll
  for (int ks = 0; ks < 2; ++ks) {
    bf16x8 ah[4], al[4];
    const int gk = ks * 8 + (l >> 4) * 2;
#pragma unroll
    for (int xf = 0; xf < 4; ++xf) {
      int n = xf * 16 + rsel;
      u32x4 p0 = *(const u32x4*)((const char*)zp + (n << 8) + ((gk ^ (n & 15)) << 4));
      u32x4 p1 = *(const u32x4*)((const char*)zp + (n << 8) + (((gk + 1) ^ (n & 15)) << 4));
      ah[xf] = mkfrag(p0, p1, SEL_HI);
      al[xf] = mkfrag(p0, p1, SEL_LO);
    }
#pragma unroll
    for (int nf = 0; nf < 8; ++nf) {
      int fg = wv * 8 + nf;
      u32x4 b0 = *(const u32x4*)(eq + (((size_t)((ks * 32 + fg) * 2 + 0)) << 8) + (l << 2));
      u32x4 b1 = *(const u32x4*)(eq + (((size_t)((ks * 32 + fg) * 2 + 1)) << 8) + (l << 2));
      bf16x8 wh = mkfrag(b0, b1, SEL_HI);
      bf16x8 wl = mkfrag(b0, b1, SEL_LO);
#pragma unroll
      for (int xf = 0; xf < 4; ++xf) {
        acc[nf][xf] = __builtin_amdgcn_mfma_f32_16x16x32_bf16(wh, ah[xf], acc[nf][xf], 0, 0, 0);
        acc[nf][xf] = __builtin_amdgcn_mfma_f32_16x16x32_bf16(wh, al[xf], acc[nf][xf], 0, 0, 0);
        acc[nf][xf] = __builtin_amdgcn_mfma_f32_16x16x32_bf16(wl, ah[xf], acc[nf][xf], 0, 0, 0);
      }
    }
  }

  // ---- per-lane enorm gather (32 k-values, reused across xf) ----
  float en[8][4];
#pragma unroll
  for (int nf = 0; nf < 8; ++nf)
#pragma unroll
    for (int r = 0; r < 4; ++r)
      en[nf][r] = enorm[wv * 128 + nf * 16 + (l >> 4) * 4 + r];

  // ---- argmin per xf block, first-min (ascending k, idx tie-break) ----
#pragma unroll
  for (int xf = 0; xf < 4; ++xf) {
    float best = 1e30f; int bidx = 0;
#pragma unroll
    for (int nf = 0; nf < 8; ++nf)
#pragma unroll
      for (int r = 0; r < 4; ++r) {
        int k = wv * 128 + nf * 16 + (l >> 4) * 4 + r;
        float dist = en[nf][r] - 2.f * acc[nf][xf][r];
        if (dist < best || (dist == best && k < bidx)) { best = dist; bidx = k; }
      }
#pragma unroll
    for (int off = 16; off <= 32; off <<= 1) {
      float ob = __shfl_xor(best, off, 64);
      int oi = __shfl_xor(bidx, off, 64);
      if (ob < best || (ob == best && oi < bidx)) { best = ob; bidx = oi; }
    }
    if (l < 16) { candd[wv][xf * 16 + l] = best; candi[wv][xf * 16 + l] = bidx; }
  }
  __syncthreads();
  if (tid < 64) {
    float best = candd[0][tid]; int bidx = candi[0][tid];
#pragma unroll
    for (int w = 1; w < 4; ++w) {
      float ob = candd[w][tid]; int oi = candi[w][tid];
      if (ob < best || (ob == best && oi < bidx)) { best = ob; bidx = oi; }
    }
    idxf[tid] = bidx;
    atomicAdd(&hist[bidx], 1u);
  }
  __syncthreads();

  // ---- z_q writeback (contiguous, coalesced) + sse from exact fp32 z ----
  float sse = 0.f;
#pragma unroll
  for (int p = 0; p < 16; ++p) {
    int idx = p * 256 + tid;
    int n = idx >> 6, d = idx & 63;
    float q = emb[idxf[n] * 64 + d];
    float z = zf[n][d];
    float df = q - z;
    sse += df * df;
    zsrc[idx] = q;
  }
#pragma unroll
  for (int off = 32; off > 0; off >>= 1) sse += __shfl_down(sse, off, 64);
  if (l == 0) atomicAdd(gsse, sse);
}

// ================= finalize =================
__global__ void fin_k(const unsigned* __restrict__ hist,
                      const float* __restrict__ gsse,
                      float* __restrict__ out) {
  __shared__ float red[512];
  int t = threadIdx.x;
  float p = (float)hist[t] * (1.f / 65536.f);
  red[t] = p * logf(p + 1e-10f);
  __syncthreads();
  for (int s = 256; s > 0; s >>= 1) {
    if (t < s) red[t] += red[t + s];
    __syncthreads();
  }
  if (t == 0) {
    out[4194304] = 1.25f * gsse[0] * (1.f / 4194304.f);
    out[4194305] = expf(-red[0]);
  }
}

extern "C" void kernel_launch(void* const* d_in, const int* in_sizes, int n_in,
                              void* d_out, int out_size, void* d_ws, size_t ws_size,
                              hipStream_t stream) {
  const float* x   = (const float*)d_in[0];
  const float* w1  = (const float*)d_in[1];
  const float* b1  = (const float*)d_in[2];
  const float* w2  = (const float*)d_in[3];
  const float* b2  = (const float*)d_in[4];
  const float* w3  = (const float*)d_in[5];
  const float* b3  = (const float*)d_in[6];
  const float* emb = (const float*)d_in[7];
  // decoder weights unused: reference output ignores x_recon

  float* out = (float*)d_out;
  unsigned* wsu = (unsigned*)d_ws;
  unsigned* h1p = wsu + H1P_OFF;
  unsigned* h2p = wsu + H2P_OFF;
  unsigned* wq2 = wsu + WP2_OFF;
  unsigned* wq3 = wsu + WP3_OFF;
  unsigned* eqp = wsu + EQ_OFF;
  float* enorm = (float*)(wsu + EN_OFF);
  unsigned* hist = wsu + HIST_OFF;
  float* gsse = (float*)(wsu + SSE_OFF);

  hipMemsetAsync(wsu + HIST_OFF, 0, (512 + 1) * sizeof(unsigned), stream);

  pack_wq2_k<<<dim3(2048), dim3(256), 0, stream>>>(w2, wq2);
  pack_wq3_k<<<dim3(768),  dim3(256), 0, stream>>>(w3, wq3);
  pack_eq_k<<<dim3(128),   dim3(256), 0, stream>>>(emb, eqp, enorm);
  halo_k<<<dim3(9408), dim3(256), 0, stream>>>(h1p, h2p);

  conv1_k<<<dim3(8, 8, 16), dim3(16, 16), 0, stream>>>(x, w1, b1, h1p);
  convmm_k<128, 16, 256, 130, 132, 2, 1, 4, 68, 4488, 1, true>
      <<<dim3(1024), dim3(256), 0, stream>>>(h1p, wq2, b2, h2p, nullptr);
  convmm_k<256, 12, 64, 66, 68, 1, 2, 2, 64, 4096, 0, false>
      <<<dim3(512), dim3(256), 0, stream>>>(h2p, wq3, b3, nullptr, out);

  vqmm_k<<<dim3(1024), dim3(256), 0, stream>>>(out, emb, eqp, enorm, hist, gsse);
  fin_k<<<dim3(1), dim3(512), 0, stream>>>(hist, gsse, out);
}

// Round 8
// 431.595 us; speedup vs baseline: 1.4701x; 1.4701x over previous
//
#include <hip/hip_runtime.h>
#include <math.h>

typedef __attribute__((ext_vector_type(8))) short bf16x8;
typedef __attribute__((ext_vector_type(4))) float f32x4;
typedef __attribute__((ext_vector_type(4))) unsigned u32x4;

// ---------------- workspace layout (u32 offsets) ----------------
#define H1P_OFF  0ull
#define H2P_OFF  35143680ull
#define WP2_OFF  53526528ull
#define WP3_OFF  54050816ull
#define EQ_OFF   54247424ull   // packed emb, lane-contiguous, 32768 u32
#define EN_OFF   54280192ull
#define HIST_OFF 54280704ull   // 8 replicas x 512 u32 = 4096
#define SSEP_OFF 54284800ull   // 1024 per-block partials
// end ~54285824 u32 (~217 MB)

__device__ inline unsigned short f2bf(float f) {
  unsigned u = __builtin_bit_cast(unsigned, f);
  return (unsigned short)((u + 0x7fffu + ((u >> 16) & 1u)) >> 16);  // RNE
}
__device__ inline float bf2f(unsigned short h) {
  return __builtin_bit_cast(float, (unsigned)h << 16);
}
__device__ inline unsigned packsplit(float v) {
  unsigned short h = f2bf(v);
  unsigned short l = f2bf(v - bf2f(h));
  return (unsigned)h | ((unsigned)l << 16);
}
__device__ inline int swz(int row, int g) {  // byte offset in a [rows][32 u32] tile
  return ((row << 7) + (g << 4)) ^ ((row & 7) << 4);
}
#define SEL_HI 0x05040100u
#define SEL_LO 0x07060302u
__device__ inline bf16x8 mkfrag(const u32x4 p, const u32x4 q, unsigned sel) {
  u32x4 r;
  r[0] = __builtin_amdgcn_perm(p[1], p[0], sel);
  r[1] = __builtin_amdgcn_perm(p[3], p[2], sel);
  r[2] = __builtin_amdgcn_perm(q[1], q[0], sel);
  r[3] = __builtin_amdgcn_perm(q[3], q[2], sel);
  return __builtin_bit_cast(bf16x8, r);
}

// ======= weight repack: lane-contiguous per (ks, frag, j) 1KB blocks =========
__global__ void pack_wq2_k(const float* __restrict__ w, unsigned* __restrict__ wq) {
  int i = blockIdx.x * 256 + threadIdx.x;
  if (i >= 524288) return;
  int e = i & 3, l = (i >> 2) & 63, j = (i >> 8) & 1, fg = (i >> 9) & 15, ks = i >> 13;
  int row = fg * 16 + (l & 15);
  int k = ks * 32 + (l >> 4) * 8 + j * 4 + e;
  wq[i] = packsplit(w[row * 2048 + k]);
}
__global__ void pack_wq3_k(const float* __restrict__ w, unsigned* __restrict__ wq) {
  int i = blockIdx.x * 256 + threadIdx.x;
  if (i >= 196608) return;
  int e = i & 3, l = (i >> 2) & 63, j = (i >> 8) & 1, fg = (i >> 9) & 3, ks = i >> 11;
  int row = fg * 16 + (l & 15);
  int k = ks * 32 + (l >> 4) * 8 + j * 4 + e;
  int ci = k / 12, rb = k - ci * 12, kh = rb >> 2, kw = rb & 3;
  wq[i] = (kw < 3) ? packsplit(w[((row * 256 + ci) * 3 + kh) * 3 + kw]) : 0u;
}
// emb repack for VQ MFMA: fg 0..31 (512 rows / 16), ks 0..1 (K=64)
__global__ void pack_eq_k(const float* __restrict__ emb, unsigned* __restrict__ eq,
                          float* __restrict__ enorm) {
  int i = blockIdx.x * 256 + threadIdx.x;
  if (i < 32768) {
    int e = i & 3, l = (i >> 2) & 63, j = (i >> 8) & 1, fg = (i >> 9) & 31, ks = i >> 14;
    int row = fg * 16 + (l & 15);
    int d = ks * 32 + (l >> 4) * 8 + j * 4 + e;
    eq[i] = packsplit(emb[row * 64 + d]);
  }
  if (i < 512) {
    float s = 0.f;
#pragma unroll
    for (int d = 0; d < 64; ++d) { float e = emb[i * 64 + d]; s += e * e; }
    enorm[i] = s;
  }
}

// ================= halo zeroing for padded activation planes =================
__global__ void halo_k(unsigned* __restrict__ h1p, unsigned* __restrict__ h2p) {
  int i = blockIdx.x * 256 + threadIdx.x;
  if (i < 2048 * 520) {
    int p = i / 520, c = i - p * 520; int r, cc;
    if (c < 132)      { r = 0;   cc = c; }
    else if (c < 264) { r = 129; cc = c - 132; }
    else if (c < 392) { r = c - 264 + 1; cc = 0; }
    else              { r = c - 392 + 1; cc = 129; }
    h1p[(size_t)p * 130 * 132 + r * 132 + cc] = 0u;
  } else {
    int j = i - 2048 * 520;
    if (j >= 4096 * 328) return;
    int p = j / 328, c = j - p * 328; int r, cc;
    if (c < 68)       { r = 0;  cc = c; }
    else if (c < 136) { r = 65; cc = c - 68; }
    else { int c2 = c - 136; int which = c2 >> 6; r = 1 + (c2 & 63);
           cc = (which == 0) ? 0 : (which == 1 ? 65 : 66); }
    h2p[(size_t)p * 66 * 68 + r * 68 + cc] = 0u;
  }
}

// ================= conv1: 3->128, 4x4 s2 p1, fp32 vector ====
__global__ __launch_bounds__(256) void conv1_k(const float* __restrict__ x,
                                               const float* __restrict__ w,
                                               const float* __restrict__ bias,
                                               unsigned* __restrict__ out) {
  const int tx = threadIdx.x, ty = threadIdx.y;
  const int tile_x = blockIdx.x, tile_y = blockIdx.y, b = blockIdx.z;
  __shared__ float xs[3][34][35];
  const int tid = ty * 16 + tx;
  const int iy0 = tile_y * 32 - 1, ix0 = tile_x * 32 - 1;
  for (int idx = tid; idx < 3 * 1156; idx += 256) {
    int ci = idx / 1156; int rem = idx - ci * 1156;
    int r = rem / 34;    int c = rem - r * 34;
    int iy = iy0 + r, ix = ix0 + c;
    float v = 0.f;
    if (iy >= 0 && iy < 256 && ix >= 0 && ix < 256)
      v = x[((b * 3 + ci) * 256 + iy) * 256 + ix];
    xs[ci][r][c] = v;
  }
  __syncthreads();
  float p[48];
#pragma unroll
  for (int ci = 0; ci < 3; ++ci)
#pragma unroll
    for (int kh = 0; kh < 4; ++kh)
#pragma unroll
      for (int kw = 0; kw < 4; ++kw)
        p[ci * 16 + kh * 4 + kw] = xs[ci][2 * ty + kh][2 * tx + kw];
  const int Y = tile_y * 16 + ty, X = tile_x * 16 + tx;
  for (int co = 0; co < 128; ++co) {
    float acc = bias[co];
#pragma unroll
    for (int t = 0; t < 48; ++t) acc += p[t] * w[co * 48 + t];
    float v = acc > 0.f ? acc : 0.f;
    out[((size_t)(b * 128 + co) * 130 + (Y + 1)) * 132 + (X + 1)] = packsplit(v);
  }
}

// ====== pipelined implicit-GEMM conv, split-bf16 MFMA (unchanged from R5) =====
template <int IC, int KHW, int OC, int IHP, int IWP, int S, int NWX, int NWC,
          int OSR, int OSP, int OPAD, bool SPLIT_OUT>
__global__ __launch_bounds__(256, 2) void convmm_k(const unsigned* __restrict__ inp,
                                                   const unsigned* __restrict__ wq,
                                                   const float* __restrict__ bias,
                                                   unsigned* __restrict__ outp,
                                                   float* __restrict__ outf) {
  constexpr int K = IC * KHW;
  constexpr int KSTEPS = K / 32;
  constexpr int FGTOT = OC / 16;
  constexpr int NFRAG = OC / NWC / 16;
  constexpr int MR = 64 * NWX;
  constexpr int CELLS = MR / 32;
  constexpr int ABYTES = MR * 128;
  constexpr int LOG2NWX = (NWX == 2) ? 1 : 0;
  constexpr int YBITS = 6 - LOG2NWX;

  __shared__ char smem[2 * ABYTES];

  const int tid = threadIdx.x, l = tid & 63, wv = tid >> 6;
  const int bb = blockIdx.x >> YBITS;
  const int y0 = blockIdx.x & ((1 << YBITS) - 1);
  const int rsel = l & 15, g0 = (l >> 4) * 2;
  const int mbase = (wv & (NWX - 1)) * 64;
  const int fgbase = (wv >> LOG2NWX) * NFRAG;
  const int nbase = fgbase * 16;

  const int arow = tid & (MR - 1);
  int qs[CELLS];
  const unsigned* abase[CELLS];
#pragma unroll
  for (int c = 0; c < CELLS; ++c) {
    if constexpr (NWX == 1) qs[c] = (tid >> 6) + c * 4;
    else                    qs[c] = (tid >> 7) * 4 + c;
    if constexpr (KHW == 16) {
      int ci0 = qs[c] >> 2, kh = qs[c] & 3;
      abase[c] = inp + (((size_t)bb * IC + ci0) * IHP + (S * y0 + kh)) * IWP + S * arow;
    }
  }

  f32x4 acc[NFRAG][4];
#pragma unroll
  for (int nf = 0; nf < NFRAG; ++nf)
#pragma unroll
    for (int xf = 0; xf < 4; ++xf) acc[nf][xf] = (f32x4){0.f, 0.f, 0.f, 0.f};

  unsigned av[CELLS][4];
  u32x4 brA[NFRAG][2], brB[NFRAG][2];

  auto loadA = [&](int ks) {
#pragma unroll
    for (int c = 0; c < CELLS; ++c) {
      if constexpr (KHW == 16) {
        const unsigned* p = abase[c];
        av[c][0] = p[0]; av[c][1] = p[1]; av[c][2] = p[2]; av[c][3] = p[3];
        abase[c] += (size_t)2 * IHP * IWP;
      } else {
        int k = ks * 32 + qs[c] * 4;
        int ci = (k * 5462) >> 16;
        int rb = k - ci * 12;
        int kh = rb >> 2;
        int yl = arow >> 6, x = arow & 63;
        const unsigned* p = inp + (((size_t)bb * IC + ci) * IHP + (y0 * 2 + yl + kh)) * IWP + x;
        av[c][0] = p[0]; av[c][1] = p[1]; av[c][2] = p[2]; av[c][3] = p[3];
      }
    }
  };
  auto writeA = [&](int buf) {
    char* base = smem + buf * ABYTES;
#pragma unroll
    for (int c = 0; c < CELLS; ++c) {
      int wb = (arow << 7) + ((qs[c] ^ (arow & 7)) << 4);
      *(u32x4*)(base + wb) = *(u32x4*)&av[c][0];
    }
  };
  auto loadB = [&](int ks, u32x4 (&br)[NFRAG][2]) {
#pragma unroll
    for (int nf = 0; nf < NFRAG; ++nf)
#pragma unroll
      for (int j = 0; j < 2; ++j)
        br[nf][j] = *(const u32x4*)(wq + (((size_t)((ks * FGTOT + fgbase + nf) * 2 + j)) << 8)
                                       + (l << 2));
  };
  auto step = [&](int ks, u32x4 (&cur)[NFRAG][2], u32x4 (&nxt)[NFRAG][2]) {
    const bool has = (ks + 1 < KSTEPS);
    if (has) { loadB(ks + 1, nxt); loadA(ks + 1); }
    const char* bA = smem + (ks & 1) * ABYTES;
    u32x4 ar[4][2];
#pragma unroll
    for (int xf = 0; xf < 4; ++xf) {
      int row = mbase + xf * 16 + rsel;
      ar[xf][0] = *(const u32x4*)(bA + swz(row, g0));
      ar[xf][1] = *(const u32x4*)(bA + swz(row, g0 + 1));
    }
    bf16x8 ah[4], al[4];
#pragma unroll
    for (int xf = 0; xf < 4; ++xf) {
      ah[xf] = mkfrag(ar[xf][0], ar[xf][1], SEL_HI);
      al[xf] = mkfrag(ar[xf][0], ar[xf][1], SEL_LO);
    }
#pragma unroll
    for (int nf = 0; nf < NFRAG; ++nf) {
      bf16x8 wh = mkfrag(cur[nf][0], cur[nf][1], SEL_HI);
      bf16x8 wl = mkfrag(cur[nf][0], cur[nf][1], SEL_LO);
#pragma unroll
      for (int xf = 0; xf < 4; ++xf) {
        acc[nf][xf] = __builtin_amdgcn_mfma_f32_16x16x32_bf16(wh, ah[xf], acc[nf][xf], 0, 0, 0);
        acc[nf][xf] = __builtin_amdgcn_mfma_f32_16x16x32_bf16(wh, al[xf], acc[nf][xf], 0, 0, 0);
        acc[nf][xf] = __builtin_amdgcn_mfma_f32_16x16x32_bf16(wl, ah[xf], acc[nf][xf], 0, 0, 0);
      }
    }
    if (has) writeA((ks & 1) ^ 1);
    __syncthreads();
  };

  loadB(0, brA);
  loadA(0);
  writeA(0);
  __syncthreads();

#pragma unroll 1
  for (int ks = 0; ks < KSTEPS; ks += 2) {
    step(ks, brA, brB);
    step(ks + 1, brB, brA);
  }

#pragma unroll
  for (int nf = 0; nf < NFRAG; ++nf) {
    int n0 = nbase + nf * 16 + (l >> 4) * 4;
#pragma unroll
    for (int xf = 0; xf < 4; ++xf) {
      int m = mbase + xf * 16 + rsel;
      int yl = m >> 6, xo = m & 63;
      int yout = y0 * NWX + yl;
#pragma unroll
      for (int r = 0; r < 4; ++r) {
        float v = acc[nf][xf][r] + bias[n0 + r];
        if constexpr (SPLIT_OUT) {
          if (v < 0.f) v = 0.f;
          outp[((size_t)bb * OC + n0 + r) * OSP + (size_t)(yout + OPAD) * OSR + (xo + OPAD)] =
              packsplit(v);
        } else {
          outf[((size_t)bb * OC + n0 + r) * OSP + (size_t)yout * OSR + xo] = v;
        }
      }
    }
  }
}

// ============ VQ via MFMA: dists GEMM + argmin + quantize + hist + sse ========
// flat_z = raw reshape: each VQ vector is a contiguous x-line. Block = 64 rows.
// Histogram: LDS-aggregated, flushed to 1-of-8 replica (cuts same-line atomic
// storm ~500x). SSE: per-block partial store, no atomic.
__global__ __launch_bounds__(256, 2) void vqmm_k(float* __restrict__ zq,
                                                 const float* __restrict__ emb,
                                                 const unsigned* __restrict__ eq,
                                                 const float* __restrict__ enorm,
                                                 unsigned* __restrict__ hist,
                                                 float* __restrict__ ssep) {
  const int tid = threadIdx.x, l = tid & 63, wv = tid >> 6;
  float* zsrc = zq + (size_t)blockIdx.x * 4096;   // rows [blk*64, blk*64+64)

  __shared__ float zf[64][64];       // fp32 copy [n][d]
  __shared__ unsigned zp[4096];      // packed swizzled [n][d-groups]
  __shared__ float candd[4][64];
  __shared__ int   candi[4][64];
  __shared__ int   idxf[64];
  __shared__ unsigned hcnt[512];
  __shared__ float wsse[4];

  for (int i = tid; i < 512; i += 256) hcnt[i] = 0;

  // ---- stage 1: fully-contiguous fp32 load (16KB) ----
#pragma unroll
  for (int p = 0; p < 4; ++p) {
    int idx = p * 256 + tid;               // float4 index
    float4 v = *(const float4*)(zsrc + (size_t)idx * 4);
    int n = idx >> 4, d0 = (idx & 15) * 4;
    zf[n][d0 + 0] = v.x; zf[n][d0 + 1] = v.y;
    zf[n][d0 + 2] = v.z; zf[n][d0 + 3] = v.w;
  }
  __syncthreads();
  // ---- stage 2: pack + swizzle (row n, d-group g stored at g^(n&15)) ----
#pragma unroll
  for (int p = 0; p < 16; ++p) {
    int idx = p * 256 + tid;
    int n = idx >> 6, d = idx & 63;
    zp[(n << 6) + ((((d >> 2) ^ (n & 15)) << 2) | (d & 3))] = packsplit(zf[n][d]);
  }
  __syncthreads();

  // ---- MFMA: wave wv covers embeddings [wv*128, wv*128+128) ----
  f32x4 acc[8][4];
#pragma unroll
  for (int nf = 0; nf < 8; ++nf)
#pragma unroll
    for (int xf = 0; xf < 4; ++xf) acc[nf][xf] = (f32x4){0.f, 0.f, 0.f, 0.f};

  const int rsel = l & 15;
#pragma unroll
  for (int ks = 0; ks < 2; ++ks) {
    bf16x8 ah[4], al[4];
    const int gk = ks * 8 + (l >> 4) * 2;
#pragma unroll
    for (int xf = 0; xf < 4; ++xf) {
      int n = xf * 16 + rsel;
      u32x4 p0 = *(const u32x4*)((const char*)zp + (n << 8) + ((gk ^ (n & 15)) << 4));
      u32x4 p1 = *(const u32x4*)((const char*)zp + (n << 8) + (((gk + 1) ^ (n & 15)) << 4));
      ah[xf] = mkfrag(p0, p1, SEL_HI);
      al[xf] = mkfrag(p0, p1, SEL_LO);
    }
#pragma unroll
    for (int nf = 0; nf < 8; ++nf) {
      int fg = wv * 8 + nf;
      u32x4 b0 = *(const u32x4*)(eq + (((size_t)((ks * 32 + fg) * 2 + 0)) << 8) + (l << 2));
      u32x4 b1 = *(const u32x4*)(eq + (((size_t)((ks * 32 + fg) * 2 + 1)) << 8) + (l << 2));
      bf16x8 wh = mkfrag(b0, b1, SEL_HI);
      bf16x8 wl = mkfrag(b0, b1, SEL_LO);
#pragma unroll
      for (int xf = 0; xf < 4; ++xf) {
        acc[nf][xf] = __builtin_amdgcn_mfma_f32_16x16x32_bf16(wh, ah[xf], acc[nf][xf], 0, 0, 0);
        acc[nf][xf] = __builtin_amdgcn_mfma_f32_16x16x32_bf16(wh, al[xf], acc[nf][xf], 0, 0, 0);
        acc[nf][xf] = __builtin_amdgcn_mfma_f32_16x16x32_bf16(wl, ah[xf], acc[nf][xf], 0, 0, 0);
      }
    }
  }

  // ---- per-lane enorm gather (32 k-values, reused across xf) ----
  float en[8][4];
#pragma unroll
  for (int nf = 0; nf < 8; ++nf)
#pragma unroll
    for (int r = 0; r < 4; ++r)
      en[nf][r] = enorm[wv * 128 + nf * 16 + (l >> 4) * 4 + r];

  // ---- argmin per xf block, first-min (ascending k, idx tie-break) ----
#pragma unroll
  for (int xf = 0; xf < 4; ++xf) {
    float best = 1e30f; int bidx = 0;
#pragma unroll
    for (int nf = 0; nf < 8; ++nf)
#pragma unroll
      for (int r = 0; r < 4; ++r) {
        int k = wv * 128 + nf * 16 + (l >> 4) * 4 + r;
        float dist = en[nf][r] - 2.f * acc[nf][xf][r];
        if (dist < best || (dist == best && k < bidx)) { best = dist; bidx = k; }
      }
#pragma unroll
    for (int off = 16; off <= 32; off <<= 1) {
      float ob = __shfl_xor(best, off, 64);
      int oi = __shfl_xor(bidx, off, 64);
      if (ob < best || (ob == best && oi < bidx)) { best = ob; bidx = oi; }
    }
    if (l < 16) { candd[wv][xf * 16 + l] = best; candi[wv][xf * 16 + l] = bidx; }
  }
  __syncthreads();
  if (tid < 64) {
    float best = candd[0][tid]; int bidx = candi[0][tid];
#pragma unroll
    for (int w = 1; w < 4; ++w) {
      float ob = candd[w][tid]; int oi = candi[w][tid];
      if (ob < best || (ob == best && oi < bidx)) { best = ob; bidx = oi; }
    }
    idxf[tid] = bidx;
    atomicAdd(&hcnt[bidx], 1u);          // LDS aggregation
  }
  __syncthreads();

  // ---- z_q writeback (contiguous, coalesced) + sse from exact fp32 z ----
  float sse = 0.f;
#pragma unroll
  for (int p = 0; p < 16; ++p) {
    int idx = p * 256 + tid;
    int n = idx >> 6, d = idx & 63;
    float q = emb[idxf[n] * 64 + d];
    float z = zf[n][d];
    float df = q - z;
    sse += df * df;
    zsrc[idx] = q;
  }
#pragma unroll
  for (int off = 32; off > 0; off >>= 1) sse += __shfl_down(sse, off, 64);
  if (l == 0) wsse[wv] = sse;

  // ---- flush LDS histogram into 1-of-8 replica (few, count-carrying atomics) ----
  unsigned* hr = hist + ((blockIdx.x & 7) << 9);
  __syncthreads();
  for (int i = tid; i < 512; i += 256)
    if (hcnt[i]) atomicAdd(&hr[i], hcnt[i]);
  if (tid == 0) ssep[blockIdx.x] = wsse[0] + wsse[1] + wsse[2] + wsse[3];
}

// ================= finalize: reduce replicas + partials =================
__global__ void fin_k(const unsigned* __restrict__ hist,
                      const float* __restrict__ ssep,
                      float* __restrict__ out) {
  __shared__ float red[512];
  __shared__ float sred[512];
  int t = threadIdx.x;
  sred[t] = ssep[t] + ssep[t + 512];
  unsigned c = 0;
#pragma unroll
  for (int r = 0; r < 8; ++r) c += hist[(r << 9) + t];
  float p = (float)c * (1.f / 65536.f);
  red[t] = p * logf(p + 1e-10f);
  __syncthreads();
  for (int s = 256; s > 0; s >>= 1) {
    if (t < s) { red[t] += red[t + s]; sred[t] += sred[t + s]; }
    __syncthreads();
  }
  if (t == 0) {
    out[4194304] = 1.25f * sred[0] * (1.f / 4194304.f);
    out[4194305] = expf(-red[0]);
  }
}

extern "C" void kernel_launch(void* const* d_in, const int* in_sizes, int n_in,
                              void* d_out, int out_size, void* d_ws, size_t ws_size,
                              hipStream_t stream) {
  const float* x   = (const float*)d_in[0];
  const float* w1  = (const float*)d_in[1];
  const float* b1  = (const float*)d_in[2];
  const float* w2  = (const float*)d_in[3];
  const float* b2  = (const float*)d_in[4];
  const float* w3  = (const float*)d_in[5];
  const float* b3  = (const float*)d_in[6];
  const float* emb = (const float*)d_in[7];
  // decoder weights unused: reference output ignores x_recon

  float* out = (float*)d_out;
  unsigned* wsu = (unsigned*)d_ws;
  unsigned* h1p = wsu + H1P_OFF;
  unsigned* h2p = wsu + H2P_OFF;
  unsigned* wq2 = wsu + WP2_OFF;
  unsigned* wq3 = wsu + WP3_OFF;
  unsigned* eqp = wsu + EQ_OFF;
  float* enorm = (float*)(wsu + EN_OFF);
  unsigned* hist = wsu + HIST_OFF;
  float* ssep = (float*)(wsu + SSEP_OFF);

  hipMemsetAsync(wsu + HIST_OFF, 0, 4096 * sizeof(unsigned), stream);

  pack_wq2_k<<<dim3(2048), dim3(256), 0, stream>>>(w2, wq2);
  pack_wq3_k<<<dim3(768),  dim3(256), 0, stream>>>(w3, wq3);
  pack_eq_k<<<dim3(128),   dim3(256), 0, stream>>>(emb, eqp, enorm);
  halo_k<<<dim3(9408), dim3(256), 0, stream>>>(h1p, h2p);

  conv1_k<<<dim3(8, 8, 16), dim3(16, 16), 0, stream>>>(x, w1, b1, h1p);
  convmm_k<128, 16, 256, 130, 132, 2, 1, 4, 68, 4488, 1, true>
      <<<dim3(1024), dim3(256), 0, stream>>>(h1p, wq2, b2, h2p, nullptr);
  convmm_k<256, 12, 64, 66, 68, 1, 2, 2, 64, 4096, 0, false>
      <<<dim3(512), dim3(256), 0, stream>>>(h2p, wq3, b3, nullptr, out);

  vqmm_k<<<dim3(1024), dim3(256), 0, stream>>>(out, emb, eqp, enorm, hist, ssep);
  fin_k<<<dim3(1), dim3(512), 0, stream>>>(hist, ssep, out);
}